// Round 1
// baseline (146.926 us; speedup 1.0000x reference)
//
#include <hip/hip_runtime.h>
#include <hip/hip_bf16.h>

#define NB 2
#define NH 8
#define NS 2048
#define ND 64
#define QBLK 64
#define KBLK 64
#define NKT (NS / KBLK)   // 32
#define LDST 72           // LDS row stride in f16 elements (144 B) — conflict-friendly

typedef _Float16 f16x4 __attribute__((ext_vector_type(4)));
typedef _Float16 f16x8 __attribute__((ext_vector_type(8)));
typedef float    f32x4 __attribute__((ext_vector_type(4)));

#define MFMA16(A, Bf, C) __builtin_amdgcn_mfma_f32_16x16x32_f16((A), (Bf), (C), 0, 0, 0)

__global__ __launch_bounds__(256)
void sdpa_kernel(const float* __restrict__ Qg, const float* __restrict__ Kg,
                 const float* __restrict__ Vg, float* __restrict__ Og,
                 float* __restrict__ Ag)
{
    const int tid  = threadIdx.x;
    const int w    = tid >> 6;     // wave 0..3
    const int lane = tid & 63;
    const int lg   = lane >> 4;    // 0..3
    const int lc   = lane & 15;    // 0..15
    const int qt   = blockIdx.x;   // 0..31
    const int bh   = blockIdx.y;   // 0..15

    const size_t base = (size_t)bh * NS * ND;
    const float* Qp = Qg + base + (size_t)qt * QBLK * ND;
    const float* Kp = Kg + base;
    const float* Vp = Vg + base;
    float*       Op = Og + base + (size_t)qt * QBLK * ND;
    float*       Ap = Ag + (size_t)bh * NS * NS + (size_t)qt * QBLK * NS;

    __shared__ __align__(16) _Float16 Qs[QBLK * LDST];
    __shared__ __align__(16) _Float16 Ks[KBLK * LDST];
    __shared__ __align__(16) _Float16 VT[ND * LDST];
    __shared__ __align__(16) _Float16 Ps[QBLK * LDST];

    // ---- stage Q tile (scaled by 1/T = 1/8, exact) as f16 ----
    {
        const int row = tid >> 4;          // 0..15
        const int d0  = (tid & 15) * 4;
        #pragma unroll
        for (int it = 0; it < 4; ++it) {
            const int r = row + 16 * it;
            float4 f = *(const float4*)&Qp[(size_t)r * ND + d0];
            f16x4 h = { (_Float16)(f.x * 0.125f), (_Float16)(f.y * 0.125f),
                        (_Float16)(f.z * 0.125f), (_Float16)(f.w * 0.125f) };
            *(f16x4*)&Qs[r * LDST + d0] = h;
        }
    }
    __syncthreads();

    const int q = 16 * w + lc;   // this lane's query row (within tile)
    // Q B-fragments (constant for whole kernel): B[k=d][col=q], k contiguous
    const f16x8 qf0 = *(const f16x8*)&Qs[q * LDST + 8 * lg];
    const f16x8 qf1 = *(const f16x8*)&Qs[q * LDST + 8 * lg + 32];

    const f32x4 vzero = {0.f, 0.f, 0.f, 0.f};

    float m = -3.0e38f;
    float lsum = 0.0f;

    // ================= PASS A: running row-max and sum-exp =================
    for (int kt = 0; kt < NKT; ++kt) {
        __syncthreads();
        {   // stage K tile [key][d] as f16
            const int row = tid >> 4;
            const int d0  = (tid & 15) * 4;
            #pragma unroll
            for (int it = 0; it < 4; ++it) {
                const int r = row + 16 * it;
                float4 f = *(const float4*)&Kp[(size_t)(kt * KBLK + r) * ND + d0];
                f16x4 h = { (_Float16)f.x, (_Float16)f.y, (_Float16)f.z, (_Float16)f.w };
                *(f16x4*)&Ks[r * LDST + d0] = h;
            }
        }
        __syncthreads();

        // S^T tile = K · Q : rows = keys (4 sub-tiles), cols = q (this wave's 16)
        f32x4 sacc[4];
        #pragma unroll
        for (int mt = 0; mt < 4; ++mt) {
            sacc[mt] = vzero;
            f16x8 a0 = *(const f16x8*)&Ks[(16 * mt + lc) * LDST + 8 * lg];
            f16x8 a1 = *(const f16x8*)&Ks[(16 * mt + lc) * LDST + 8 * lg + 32];
            sacc[mt] = MFMA16(a0, qf0, sacc[mt]);
            sacc[mt] = MFMA16(a1, qf1, sacc[mt]);
        }

        // online softmax stats for this lane's q-row
        float tmax = -3.0e38f;
        #pragma unroll
        for (int mt = 0; mt < 4; ++mt)
            #pragma unroll
            for (int r2 = 0; r2 < 4; ++r2)
                tmax = fmaxf(tmax, sacc[mt][r2]);
        tmax = fmaxf(tmax, __shfl_xor(tmax, 16));
        tmax = fmaxf(tmax, __shfl_xor(tmax, 32));

        const float mnew = fmaxf(m, tmax);
        float tsum = 0.f;
        #pragma unroll
        for (int mt = 0; mt < 4; ++mt)
            #pragma unroll
            for (int r2 = 0; r2 < 4; ++r2)
                tsum += __expf(sacc[mt][r2] - mnew);
        tsum += __shfl_xor(tsum, 16);
        tsum += __shfl_xor(tsum, 32);

        lsum = lsum * __expf(m - mnew) + tsum;
        m = mnew;
    }
    const float inv_l = 1.0f / lsum;

    // O^T accumulators: 4 d-subtiles x f32x4
    f32x4 acc_o[4];
    #pragma unroll
    for (int mt = 0; mt < 4; ++mt) acc_o[mt] = vzero;

    // ================= PASS B: attn write + PV =================
    for (int kt = 0; kt < NKT; ++kt) {
        __syncthreads();
        {   // stage K tile
            const int row = tid >> 4;
            const int d0  = (tid & 15) * 4;
            #pragma unroll
            for (int it = 0; it < 4; ++it) {
                const int r = row + 16 * it;
                float4 f = *(const float4*)&Kp[(size_t)(kt * KBLK + r) * ND + d0];
                f16x4 h = { (_Float16)f.x, (_Float16)f.y, (_Float16)f.z, (_Float16)f.w };
                *(f16x4*)&Ks[r * LDST + d0] = h;
            }
        }
        {   // stage V^T tile [d][key]: lane = d, coalesced 256B row reads
            const int d = lane;
            #pragma unroll
            for (int it = 0; it < 4; ++it) {
                const int kb = 16 * it + 4 * w;
                f16x4 h;
                #pragma unroll
                for (int j = 0; j < 4; ++j)
                    h[j] = (_Float16)Vp[(size_t)(kt * KBLK + kb + j) * ND + d];
                *(f16x4*)&VT[d * LDST + kb] = h;
            }
        }
        __syncthreads();

        // recompute S^T tile
        f32x4 sacc[4];
        #pragma unroll
        for (int mt = 0; mt < 4; ++mt) {
            sacc[mt] = vzero;
            f16x8 a0 = *(const f16x8*)&Ks[(16 * mt + lc) * LDST + 8 * lg];
            f16x8 a1 = *(const f16x8*)&Ks[(16 * mt + lc) * LDST + 8 * lg + 32];
            sacc[mt] = MFMA16(a0, qf0, sacc[mt]);
            sacc[mt] = MFMA16(a1, qf1, sacc[mt]);
        }

        // p = exp(s-m)/l : write attn (fp32) + stash P (f16) for PV
        #pragma unroll
        for (int mt = 0; mt < 4; ++mt) {
            f32x4 p;
            #pragma unroll
            for (int r2 = 0; r2 < 4; ++r2)
                p[r2] = __expf(sacc[mt][r2] - m) * inv_l;
            *(f32x4*)&Ap[(size_t)q * NS + kt * KBLK + 16 * mt + 4 * lg] = p;
            f16x4 ph = { (_Float16)p[0], (_Float16)p[1], (_Float16)p[2], (_Float16)p[3] };
            *(f16x4*)&Ps[q * LDST + 16 * mt + 4 * lg] = ph;
        }
        // wave-private P rows: order LDS writes before reads (no barrier needed)
        asm volatile("s_waitcnt lgkmcnt(0)" ::: "memory");

        // PV: O^T += V^T · P^T
        const f16x8 b0 = *(const f16x8*)&Ps[q * LDST + 8 * lg];
        const f16x8 b1 = *(const f16x8*)&Ps[q * LDST + 8 * lg + 32];
        #pragma unroll
        for (int mt = 0; mt < 4; ++mt) {
            f16x8 a0 = *(const f16x8*)&VT[(16 * mt + lc) * LDST + 8 * lg];
            f16x8 a1 = *(const f16x8*)&VT[(16 * mt + lc) * LDST + 8 * lg + 32];
            acc_o[mt] = MFMA16(a0, b0, acc_o[mt]);
            acc_o[mt] = MFMA16(a1, b1, acc_o[mt]);
        }
    }

    // write output: lane holds O^T[d = 16mt+4lg+r][q] -> out[q][d], float4 per mt
    #pragma unroll
    for (int mt = 0; mt < 4; ++mt)
        *(f32x4*)&Op[(size_t)q * ND + 16 * mt + 4 * lg] = acc_o[mt];
}

extern "C" void kernel_launch(void* const* d_in, const int* in_sizes, int n_in,
                              void* d_out, int out_size, void* d_ws, size_t ws_size,
                              hipStream_t stream) {
    const float* q = (const float*)d_in[0];
    const float* k = (const float*)d_in[1];
    const float* v = (const float*)d_in[2];
    float* out  = (float*)d_out;
    float* attn = out + (size_t)NB * NH * NS * ND;  // outputs concatenated: (output, attn)

    dim3 grid(NS / QBLK, NB * NH);
    sdpa_kernel<<<grid, 256, 0, stream>>>(q, k, v, out, attn);
}

// Round 2
// 131.040 us; speedup vs baseline: 1.1212x; 1.1212x over previous
//
#include <hip/hip_runtime.h>
#include <hip/hip_bf16.h>

#define NB 2
#define NH 8
#define NS 2048
#define ND 64
#define QBLK 64
#define KBLK 64
#define NKT (NS / KBLK)   // 32
#define LDST 72           // LDS row stride (f16): 144 B, 16B-aligned, floor-optimal b128 reads

typedef _Float16 f16x4 __attribute__((ext_vector_type(4)));
typedef _Float16 f16x8 __attribute__((ext_vector_type(8)));
typedef float    f32x4 __attribute__((ext_vector_type(4)));

#define MFMA16(A, Bf, C) __builtin_amdgcn_mfma_f32_16x16x32_f16((A), (Bf), (C), 0, 0, 0)

__global__ __launch_bounds__(256)
void sdpa_kernel(const float* __restrict__ Qg, const float* __restrict__ Kg,
                 const float* __restrict__ Vg, float* __restrict__ Og,
                 float* __restrict__ Ag)
{
    const int tid  = threadIdx.x;
    const int w    = tid >> 6;     // wave 0..3
    const int lane = tid & 63;
    const int lg   = lane >> 4;    // 0..3
    const int lc   = lane & 15;    // 0..15
    const int qt   = blockIdx.x;   // 0..31
    const int bh   = blockIdx.y;   // 0..15

    const size_t base = (size_t)bh * NS * ND;
    const float* Qp = Qg + base + (size_t)qt * QBLK * ND;
    const float* Kp = Kg + base;
    const float* Vp = Vg + base;
    float*       Op = Og + base + (size_t)qt * QBLK * ND;
    float*       Ap = Ag + (size_t)bh * NS * NS + (size_t)qt * QBLK * NS;

    __shared__ __align__(16) _Float16 Qs[QBLK * LDST];
    __shared__ __align__(16) _Float16 Ks[KBLK * LDST];
    __shared__ __align__(16) _Float16 VT[ND * LDST];
    __shared__ __align__(16) _Float16 Ps[QBLK * LDST];

    const int srow = tid >> 4;          // 0..3
    const int sd0  = (tid & 15) * 4;    // 0..60

    // ---- stage Q tile (scaled by 1/T = 1/8, exact) as f16 ----
    #pragma unroll
    for (int it = 0; it < 4; ++it) {
        const int r = srow + 16 * it;
        float4 f = *(const float4*)&Qp[(size_t)r * ND + sd0];
        f16x4 h = { (_Float16)(f.x * 0.125f), (_Float16)(f.y * 0.125f),
                    (_Float16)(f.z * 0.125f), (_Float16)(f.w * 0.125f) };
        *(f16x4*)&Qs[r * LDST + sd0] = h;
    }
    __syncthreads();

    const int q = 16 * w + lc;   // this lane's query row (within tile)
    const f16x8 qf0 = *(const f16x8*)&Qs[q * LDST + 8 * lg];
    const f16x8 qf1 = *(const f16x8*)&Qs[q * LDST + 8 * lg + 32];

    // ---- staging helpers (coalesced loads; named reg sets for pipelining) ----
    auto loadK = [&](float4 (&d)[4], int kt_) {
        #pragma unroll
        for (int it = 0; it < 4; ++it)
            d[it] = *(const float4*)&Kp[(size_t)(kt_ * KBLK + srow + 16 * it) * ND + sd0];
    };
    auto writeK = [&](const float4 (&s)[4]) {
        #pragma unroll
        for (int it = 0; it < 4; ++it) {
            f16x4 h = { (_Float16)s[it].x, (_Float16)s[it].y,
                        (_Float16)s[it].z, (_Float16)s[it].w };
            *(f16x4*)&Ks[(srow + 16 * it) * LDST + sd0] = h;
        }
    };
    auto loadV = [&](float4 (&d)[4], int kt_) {
        #pragma unroll
        for (int it = 0; it < 4; ++it)
            d[it] = *(const float4*)&Vp[(size_t)(kt_ * KBLK + srow + 16 * it) * ND + sd0];
    };
    auto writeVT = [&](const float4 (&s)[4]) {   // LDS write-side transpose (u16 scatter)
        #pragma unroll
        for (int it = 0; it < 4; ++it) {
            const int kk = srow + 16 * it;
            VT[(sd0 + 0) * LDST + kk] = (_Float16)s[it].x;
            VT[(sd0 + 1) * LDST + kk] = (_Float16)s[it].y;
            VT[(sd0 + 2) * LDST + kk] = (_Float16)s[it].z;
            VT[(sd0 + 3) * LDST + kk] = (_Float16)s[it].w;
        }
    };

    auto qkT = [&](f32x4 (&sacc)[4]) {   // S^T tile: rows=keys, cols=q
        #pragma unroll
        for (int mt = 0; mt < 4; ++mt) {
            f32x4 z = {0.f, 0.f, 0.f, 0.f};
            f16x8 a0 = *(const f16x8*)&Ks[(16 * mt + lc) * LDST + 8 * lg];
            f16x8 a1 = *(const f16x8*)&Ks[(16 * mt + lc) * LDST + 8 * lg + 32];
            z = MFMA16(a0, qf0, z);
            z = MFMA16(a1, qf1, z);
            sacc[mt] = z;
        }
    };

    float m = -3.0e38f, lsum = 0.0f;

    auto stats = [&]() {   // online softmax stats for this lane's q-row
        f32x4 sacc[4];
        qkT(sacc);
        float tmax = -3.0e38f;
        #pragma unroll
        for (int mt = 0; mt < 4; ++mt)
            #pragma unroll
            for (int r2 = 0; r2 < 4; ++r2)
                tmax = fmaxf(tmax, sacc[mt][r2]);
        tmax = fmaxf(tmax, __shfl_xor(tmax, 16));
        tmax = fmaxf(tmax, __shfl_xor(tmax, 32));
        const float mnew = fmaxf(m, tmax);
        float tsum = 0.f;
        #pragma unroll
        for (int mt = 0; mt < 4; ++mt)
            #pragma unroll
            for (int r2 = 0; r2 < 4; ++r2)
                tsum += __expf(sacc[mt][r2] - mnew);
        tsum += __shfl_xor(tsum, 16);
        tsum += __shfl_xor(tsum, 32);
        lsum = lsum * __expf(m - mnew) + tsum;
        m = mnew;
    };

    // ================= PASS A: running row-max and sum-exp (pipelined) =================
    {
        float4 ka[4], kb[4];
        loadK(ka, 0);
        for (int kt = 0; kt < NKT; kt += 2) {
            loadK(kb, kt + 1);
            __syncthreads();
            writeK(ka);
            __syncthreads();
            stats();
            loadK(ka, (kt + 2 < NKT) ? kt + 2 : 0);
            __syncthreads();
            writeK(kb);
            __syncthreads();
            stats();
        }
    }
    const float inv_l = 1.0f / lsum;

    f32x4 acc_o[4];
    #pragma unroll
    for (int mt = 0; mt < 4; ++mt) acc_o[mt] = {0.f, 0.f, 0.f, 0.f};

    auto passB = [&](int kt) {
        f32x4 sacc[4];
        qkT(sacc);
        // p = exp(s-m)/l : write attn (fp32) + stash P (f16) for PV
        #pragma unroll
        for (int mt = 0; mt < 4; ++mt) {
            f32x4 p;
            #pragma unroll
            for (int r2 = 0; r2 < 4; ++r2)
                p[r2] = __expf(sacc[mt][r2] - m) * inv_l;
            *(f32x4*)&Ap[(size_t)q * NS + kt * KBLK + 16 * mt + 4 * lg] = p;
            f16x4 ph = { (_Float16)p[0], (_Float16)p[1], (_Float16)p[2], (_Float16)p[3] };
            *(f16x4*)&Ps[q * LDST + 16 * mt + 4 * lg] = ph;
        }
        // wave-private P rows: order LDS writes before reads (no barrier needed)
        asm volatile("s_waitcnt lgkmcnt(0)" ::: "memory");
        const f16x8 b0 = *(const f16x8*)&Ps[q * LDST + 8 * lg];
        const f16x8 b1 = *(const f16x8*)&Ps[q * LDST + 8 * lg + 32];
        #pragma unroll
        for (int mt = 0; mt < 4; ++mt) {
            f16x8 a0 = *(const f16x8*)&VT[(16 * mt + lc) * LDST + 8 * lg];
            f16x8 a1 = *(const f16x8*)&VT[(16 * mt + lc) * LDST + 8 * lg + 32];
            acc_o[mt] = MFMA16(a0, b0, acc_o[mt]);
            acc_o[mt] = MFMA16(a1, b1, acc_o[mt]);
        }
    };

    // ================= PASS B: attn write + PV (pipelined) =================
    {
        float4 ka[4], kb[4], va[4], vb[4];
        loadK(ka, 0); loadV(va, 0);
        for (int kt = 0; kt < NKT; kt += 2) {
            loadK(kb, kt + 1); loadV(vb, kt + 1);
            __syncthreads();
            writeK(ka); writeVT(va);
            __syncthreads();
            passB(kt);
            const int kt2 = (kt + 2 < NKT) ? kt + 2 : 0;
            loadK(ka, kt2); loadV(va, kt2);
            __syncthreads();
            writeK(kb); writeVT(vb);
            __syncthreads();
            passB(kt + 1);
        }
    }

    // write output: lane holds O^T[d = 16mt+4lg+r][q] -> out[q][d], float4 per mt
    #pragma unroll
    for (int mt = 0; mt < 4; ++mt)
        *(f32x4*)&Op[(size_t)q * ND + 16 * mt + 4 * lg] = acc_o[mt];
}

extern "C" void kernel_launch(void* const* d_in, const int* in_sizes, int n_in,
                              void* d_out, int out_size, void* d_ws, size_t ws_size,
                              hipStream_t stream) {
    const float* q = (const float*)d_in[0];
    const float* k = (const float*)d_in[1];
    const float* v = (const float*)d_in[2];
    float* out  = (float*)d_out;
    float* attn = out + (size_t)NB * NH * NS * ND;  // outputs concatenated: (output, attn)

    dim3 grid(NS / QBLK, NB * NH);
    sdpa_kernel<<<grid, 256, 0, stream>>>(q, k, v, out, attn);
}